// Round 20
// baseline (216.444 us; speedup 1.0000x reference)
//
#include <hip/hip_runtime.h>
#include <hip/hip_bf16.h>

// EdgeConv, CSR-by-dst, bf16 intermediates:
//   abf[n] = bf16(h@W1[0:64]); bsf[n] = bf16(h@W1[64:128]+b1)
//   acc[n] = sum_{e:dst=n} relu(abf[src] + bsf[n] + e*w128)   (wave/node, lane=feat)
//   out[n] = acc[n] @ W2 + cnt[n]*b2                          (fused readlane matvec)
// R20: ILP fix in the precompute role, MINIMAL diff vs R19 (190.4us reproduced
//   baseline). R12 body's loop nest (g, nn, k4) made each node's 64 fmas ONE
//   serial chain (4cyc dep vs 2cyc issue -> ~50% stall = VALUBusy 37-46%).
//   Permuted to (g, k4, nn) with av[4] accumulators: 4 independent chains
//   interleaved -> stall hidden. wreg[64]+pins, ldgrp prefetch, store order all
//   byte-identical; per-accumulator fma sequence unchanged -> bitwise-same
//   abf/bsf. (R16 tried this + changed weight residency simultaneously -> lost
//   to vmcnt; this round changes ONLY the unroll order.)
// R17/R19 kept: padded-by-64 scatter pipeline (memset -> pre_count -> node_accum;
//   alloc/fill deleted; classic fallback). node_accum: R3 body + padded beg.

#define PRE_NPB 128   // precompute: nodes per block (4 waves x 32 nodes)
#define PADK 64       // padded path: max edges per node

typedef unsigned int u32;

#define RL(v_, sl_) __uint_as_float(__builtin_amdgcn_readlane(__float_as_uint(v_), (sl_)))

// ---------------- offset allocation, single global cursor (classic path) ----------------
__global__ __launch_bounds__(256) void alloc_offs_kernel(const int* __restrict__ counts,
                                                         int* __restrict__ gcursor,
                                                         int* __restrict__ offs, int n) {
    __shared__ int wsum[4];
    const int i    = blockIdx.x * 256 + threadIdx.x;
    const int lane = threadIdx.x & 63;
    const int wv   = threadIdx.x >> 6;

    const int c = (i < n) ? counts[i] : 0;
    int incl = c;
    #pragma unroll
    for (int d = 1; d < 64; d <<= 1) {
        int v = __shfl_up(incl, d, 64);
        if (lane >= d) incl += v;
    }
    const int excl = incl - c;
    if (lane == 63) wsum[wv] = incl;
    __syncthreads();
    if (threadIdx.x == 0) {
        const int s0 = wsum[0], s1 = wsum[1], s2 = wsum[2], s3 = wsum[3];
        const int b = atomicAdd(gcursor, s0 + s1 + s2 + s3);
        wsum[0] = b; wsum[1] = b + s0; wsum[2] = b + s0 + s1; wsum[3] = b + s0 + s1 + s2;
    }
    __syncthreads();
    if (i < n) offs[i] = wsum[wv] + excl;
}

// ---------------- single-pass non-atomic fill (classic path) ----------------
__global__ void fill_kernel(const int* __restrict__ dst, const int* __restrict__ src,
                            const float* __restrict__ e,
                            const int* __restrict__ offs, const int* __restrict__ rank,
                            int2* __restrict__ meta, int n_edges) {
    const int i = blockIdx.x * blockDim.x + threadIdx.x;
    if (i >= n_edges) return;
    const int d = dst[i];
    meta[offs[d] + rank[i]] = make_int2(src[i], __float_as_int(e[i]));
}

// ---------------- fused: precompute (blocks < pg) + count/scatter (blocks >= pg) ----------------
// precompute: lane = output feature j; two k-passes, 64-reg weight window each;
//   h rows coalesced (1 float4/lane = 4 rows/wave) + readlane broadcast;
//   loop nest (g, k4, nn) with av[4] -> 4 interleaved fma chains (ILP).
// count role: r = atomicAdd(counts[d]); padK>0 -> scatter {src,e} to
//   meta2[d*padK+r] (padded path); padK==0 -> rank[i]=r (classic path).
__global__ __launch_bounds__(256, 2) void pre_count_kernel(
    const float* __restrict__ h, const float* __restrict__ W1, const float* __restrict__ b1,
    unsigned short* __restrict__ abf, unsigned short* __restrict__ bsf, int n_nodes,
    const int* __restrict__ dst, const int* __restrict__ src, const float* __restrict__ e,
    int* __restrict__ counts, int2* __restrict__ meta2, int* __restrict__ rank,
    int n_edges, int pg, int padK)
{
    const int lane = threadIdx.x & 63;
    const int wv   = threadIdx.x >> 6;

    if ((int)blockIdx.x >= pg) {
        // ---- count (+scatter) role ----
        const int i = ((int)blockIdx.x - pg) * 256 + threadIdx.x;
        if (i < n_edges) {
            const int d = dst[i];
            const int r = atomicAdd(&counts[d], 1);
            if (padK > 0)
                meta2[(size_t)d * padK + r] = make_int2(src[i], __float_as_int(e[i]));
            else
                rank[i] = r;
        }
        return;
    }

    // ---- precompute role ----
    const int nbase = (blockIdx.x * 4 + wv) * 32;   // wave's 32 nodes
    if (nbase >= n_nodes) return;

    const float4* h4p = reinterpret_cast<const float4*>(h);

    auto ldgrp = [&](int g) -> float4 {
        float4 v = make_float4(0.f, 0.f, 0.f, 0.f);
        const int row = nbase + 4 * g + (lane >> 4);
        if (g < 8 && row < n_nodes)
            v = h4p[(size_t)(nbase + 4 * g) * 16 + lane];
        return v;
    };

    // ---- pass A: av over W1[0:64] -> abf ----
    {
        float wreg[64];
        #pragma unroll
        for (int k = 0; k < 64; ++k) wreg[k] = W1[(size_t)k * 64 + lane];
        #pragma unroll
        for (int k = 0; k < 64; ++k) asm volatile("" : "+v"(wreg[k]));

        float4 cur = ldgrp(0);
        for (int g = 0; g < 8; ++g) {
            const float4 nxt = ldgrp(g + 1);        // prefetch next group
            float av[4];
            #pragma unroll
            for (int nn = 0; nn < 4; ++nn) av[nn] = 0.f;
            #pragma unroll
            for (int k4 = 0; k4 < 16; ++k4) {       // (k4, nn): 4 indep chains
                #pragma unroll
                for (int nn = 0; nn < 4; ++nn) {
                    const int sl = nn * 16 + k4;    // imm lane after unroll
                    av[nn] = fmaf(RL(cur.x, sl), wreg[4 * k4 + 0], av[nn]);
                    av[nn] = fmaf(RL(cur.y, sl), wreg[4 * k4 + 1], av[nn]);
                    av[nn] = fmaf(RL(cur.z, sl), wreg[4 * k4 + 2], av[nn]);
                    av[nn] = fmaf(RL(cur.w, sl), wreg[4 * k4 + 3], av[nn]);
                }
            }
            #pragma unroll
            for (int nn = 0; nn < 4; ++nn) {
                const int n = nbase + 4 * g + nn;
                if (n < n_nodes) {
                    __hip_bfloat16 ab = __float2bfloat16(av[nn]);
                    abf[(size_t)n * 64 + lane] = *reinterpret_cast<unsigned short*>(&ab);
                }
            }
            cur = nxt;
        }
    }

    // ---- pass B: bv over W1[64:128] + b1 -> bsf ----
    {
        float wreg[64];
        #pragma unroll
        for (int k = 0; k < 64; ++k) wreg[k] = W1[(size_t)(64 + k) * 64 + lane];
        #pragma unroll
        for (int k = 0; k < 64; ++k) asm volatile("" : "+v"(wreg[k]));
        const float b1l = b1[lane];

        float4 cur = ldgrp(0);
        for (int g = 0; g < 8; ++g) {
            const float4 nxt = ldgrp(g + 1);
            float bv[4];
            #pragma unroll
            for (int nn = 0; nn < 4; ++nn) bv[nn] = b1l;
            #pragma unroll
            for (int k4 = 0; k4 < 16; ++k4) {
                #pragma unroll
                for (int nn = 0; nn < 4; ++nn) {
                    const int sl = nn * 16 + k4;
                    bv[nn] = fmaf(RL(cur.x, sl), wreg[4 * k4 + 0], bv[nn]);
                    bv[nn] = fmaf(RL(cur.y, sl), wreg[4 * k4 + 1], bv[nn]);
                    bv[nn] = fmaf(RL(cur.z, sl), wreg[4 * k4 + 2], bv[nn]);
                    bv[nn] = fmaf(RL(cur.w, sl), wreg[4 * k4 + 3], bv[nn]);
                }
            }
            #pragma unroll
            for (int nn = 0; nn < 4; ++nn) {
                const int n = nbase + 4 * g + nn;
                if (n < n_nodes) {
                    __hip_bfloat16 bb = __float2bfloat16(bv[nn]);
                    bsf[(size_t)n * 64 + lane] = *reinterpret_cast<unsigned short*>(&bb);
                }
            }
            cur = nxt;
        }
    }
}

// ---------------- accum: wave/node, lane=feat, register-meta + depth-8 prefetch ----------------
// (R3 body — proven 88.2-88.5us x4; beg = n*padK in padded path, offs[n] classic)
__global__ __launch_bounds__(256) void node_accum_kernel(
    const unsigned short* __restrict__ abf, const unsigned short* __restrict__ bsf,
    const float* __restrict__ W1, const float* __restrict__ W2, const float* __restrict__ b2,
    const int* __restrict__ offs, const int* __restrict__ counts,
    const int2* __restrict__ meta, float* __restrict__ out, int n_nodes, int padK)
{
    const int lane = threadIdx.x & 63;
    const int wv   = __builtin_amdgcn_readfirstlane(threadIdx.x >> 6);
    const int n    = blockIdx.x * 4 + wv;          // wave-uniform node id
    if (n >= n_nodes) return;

    const float basel = __uint_as_float((uint)bsf[(size_t)n * 64 + lane] << 16);
    const float w128l = W1[(size_t)128 * 64 + lane];
    float acc = 0.f;

    const int beg = (padK > 0) ? n * padK : offs[n];   // s_load / SALU (n uniform)
    const int np  = counts[n];                          // s_load

    // chunks of <=64 edges: meta staged into registers by ONE lane-parallel load,
    // per-edge src/e extracted with v_readlane (no memory on the gather-addr path)
    for (int c0 = 0; c0 < np; c0 += 64) {
        const int cn = min(np - c0, 64);

        int mx = 0, my = 0;
        if (lane < cn) {
            const int2 m = meta[beg + c0 + lane];   // 512B coalesced, once per chunk
            mx = m.x; my = m.y;
        }

        // pipeline slots hold the RAW zext ushort; <<16 happens at consume time
        uint x0=0,x1=0,x2=0,x3=0,x4=0,x5=0,x6=0,x7=0;

        auto ld = [&](int j, uint& x) {
            const int s = __builtin_amdgcn_readlane(mx, j);        // uniform src id
            x = (uint)abf[(size_t)s * 64 + lane];                  // saddr gather, 128B/wave
        };
        auto step = [&](int j, uint xr) {
            const float ev = __uint_as_float((uint)__builtin_amdgcn_readlane(my, j));
            const float xv = __uint_as_float(xr << 16);
            acc += fmaxf(fmaf(ev, w128l, basel) + xv, 0.f);
        };

        if (cn > 0) ld(0, x0);
        if (cn > 1) ld(1, x1);
        if (cn > 2) ld(2, x2);
        if (cn > 3) ld(3, x3);
        if (cn > 4) ld(4, x4);
        if (cn > 5) ld(5, x5);
        if (cn > 6) ld(6, x6);
        if (cn > 7) ld(7, x7);

        int i = 0;
        while (i + 16 <= cn) {
            step(i + 0, x0); ld(i + 8,  x0);
            step(i + 1, x1); ld(i + 9,  x1);
            step(i + 2, x2); ld(i + 10, x2);
            step(i + 3, x3); ld(i + 11, x3);
            step(i + 4, x4); ld(i + 12, x4);
            step(i + 5, x5); ld(i + 13, x5);
            step(i + 6, x6); ld(i + 14, x6);
            step(i + 7, x7); ld(i + 15, x7);
            i += 8;
        }
        const int r = cn - i;   // 0..15
        if (r > 0)  { step(i + 0, x0); }  if (r > 8)  { ld(i + 8,  x0); }
        if (r > 1)  { step(i + 1, x1); }  if (r > 9)  { ld(i + 9,  x1); }
        if (r > 2)  { step(i + 2, x2); }  if (r > 10) { ld(i + 10, x2); }
        if (r > 3)  { step(i + 3, x3); }  if (r > 11) { ld(i + 11, x3); }
        if (r > 4)  { step(i + 4, x4); }  if (r > 12) { ld(i + 12, x4); }
        if (r > 5)  { step(i + 5, x5); }  if (r > 13) { ld(i + 13, x5); }
        if (r > 6)  { step(i + 6, x6); }  if (r > 14) { ld(i + 14, x6); }
        if (r > 7)  { step(i + 7, x7); }
        if (r > 8)  { step(i + 8,  x0); }
        if (r > 9)  { step(i + 9,  x1); }
        if (r > 10) { step(i + 10, x2); }
        if (r > 11) { step(i + 11, x3); }
        if (r > 12) { step(i + 12, x4); }
        if (r > 13) { step(i + 13, x5); }
        if (r > 14) { step(i + 14, x6); }
    }

    // fused epilogue: out[n][lane] = sum_j acc_j * W2[j][lane] + np*b2[lane]
    float o = (float)np * b2[lane];
    #pragma unroll
    for (int j = 0; j < 64; ++j) {
        const float aj = __shfl(acc, j, 64);               // v_readlane
        o = fmaf(aj, W2[(size_t)j * 64 + lane], o);        // coalesced, L1-hot
    }
    out[(size_t)n * 64 + lane] = o;
}

extern "C" void kernel_launch(void* const* d_in, const int* in_sizes, int n_in,
                              void* d_out, int out_size, void* d_ws, size_t ws_size,
                              hipStream_t stream) {
    const float* h  = (const float*)d_in[0];
    const float* e  = (const float*)d_in[1];
    const int* src  = (const int*)d_in[2];
    const int* dst  = (const int*)d_in[3];
    const float* W1 = (const float*)d_in[4];
    const float* b1 = (const float*)d_in[5];
    const float* W2 = (const float*)d_in[6];
    const float* b2 = (const float*)d_in[7];
    float* out = (float*)d_out;

    const int n_edges = in_sizes[2];
    const int N = in_sizes[0] / 64;

    const int eb = (n_edges + 255) / 256;
    const int nb = (N + 255) / 256;
    const int pg = (N + PRE_NPB - 1) / PRE_NPB;

    // padded path needs: counts(N+8) + meta2(N*PADK int2) + abf/bsf(256N bytes)
    const size_t need_pad = ((size_t)N + 8) * sizeof(int)
                          + (size_t)N * PADK * sizeof(int2)
                          + (size_t)N * 256;

    int* counts = (int*)d_ws;

    if (ws_size >= need_pad) {
        // ---- padded path: memset -> pre_count(+scatter) -> node_accum ----
        int2* meta2 = (int2*)(counts + N + 8);
        unsigned short* abf = (unsigned short*)(meta2 + (size_t)N * PADK);
        unsigned short* bsf = abf + (size_t)64 * N;

        hipMemsetAsync(counts, 0, ((size_t)N + 8) * sizeof(int), stream);
        pre_count_kernel<<<pg + eb, 256, 0, stream>>>(h, W1, b1, abf, bsf, N,
                                                      dst, src, e, counts, meta2,
                                                      nullptr, n_edges, pg, PADK);
        node_accum_kernel<<<(N + 3) / 4, 256, 0, stream>>>(abf, bsf, W1, W2, b2,
                                                           nullptr, counts, meta2,
                                                           out, N, PADK);
    } else {
        // ---- classic R12 path (202us proven) ----
        int* gcursor = counts + N;
        int* offs    = gcursor + 8;
        int* rank    = offs + N;
        int2* meta   = (int2*)(rank + n_edges);
        unsigned short* abf = (unsigned short*)(meta + n_edges);
        unsigned short* bsf = abf + (size_t)64 * N;

        hipMemsetAsync(counts, 0, ((size_t)N + 8) * sizeof(int), stream);
        pre_count_kernel<<<pg + eb, 256, 0, stream>>>(h, W1, b1, abf, bsf, N,
                                                      dst, src, e, counts, nullptr,
                                                      rank, n_edges, pg, 0);
        alloc_offs_kernel<<<nb, 256, 0, stream>>>(counts, gcursor, offs, N);
        fill_kernel<<<eb, 256, 0, stream>>>(dst, src, e, offs, rank, meta, n_edges);
        node_accum_kernel<<<(N + 3) / 4, 256, 0, stream>>>(abf, bsf, W1, W2, b2,
                                                           offs, counts, meta,
                                                           out, N, 0);
    }
}

// Round 21
// 186.788 us; speedup vs baseline: 1.1588x; 1.1588x over previous
//
#include <hip/hip_runtime.h>
#include <hip/hip_bf16.h>

// EdgeConv, CSR-by-dst, bf16 intermediates:
//   abf[n] = bf16(h@W1[0:64]); bsf[n] = bf16(h@W1[64:128]+b1)
//   acc[n] = sum_{e:dst=n} relu(abf[src] + bsf[n] + e*w128)   (wave/node, lane=feat)
//   out[n] = acc[n] @ W2 + cnt[n]*b2                          (fused readlane matvec)
// R21 = R19 (190.4us reproduced; R20's ILP permutation refuted — chain stall was
//   already TLP-hidden, occupancy drop cost 26us) + ONE lever: W2 packed to a
//   transposed-float4 layout w2p[q][lane][4]=W2[4q+c][lane] (packed by the first
//   count-role block), so node_accum's epilogue issues 16x dwordx4 instead of
//   64x dword (W2 VMEM-issue ~42us -> ~10us; it was the kernel's top term).
//   Avoids all 5 prior epilogue failure modes: no reg array (R4/R6 spill-wrap),
//   VMEM not LDS (R7), edge loop untouched 1 node/wave (R13). fma order j=4q+c
//   ascending -> bitwise-identical output.
// pre_count: R12 body byte-for-byte (6 variants failed against it).
// pipeline: padded-by-64 scatter (R17) -> memset, pre_count, node_accum;
//   classic fallback if ws too small.

#define PRE_NPB 128   // precompute: nodes per block (4 waves x 32 nodes)
#define PADK 64       // padded path: max edges per node

typedef unsigned int u32;

// ---------------- offset allocation, single global cursor (classic path) ----------------
__global__ __launch_bounds__(256) void alloc_offs_kernel(const int* __restrict__ counts,
                                                         int* __restrict__ gcursor,
                                                         int* __restrict__ offs, int n) {
    __shared__ int wsum[4];
    const int i    = blockIdx.x * 256 + threadIdx.x;
    const int lane = threadIdx.x & 63;
    const int wv   = threadIdx.x >> 6;

    const int c = (i < n) ? counts[i] : 0;
    int incl = c;
    #pragma unroll
    for (int d = 1; d < 64; d <<= 1) {
        int v = __shfl_up(incl, d, 64);
        if (lane >= d) incl += v;
    }
    const int excl = incl - c;
    if (lane == 63) wsum[wv] = incl;
    __syncthreads();
    if (threadIdx.x == 0) {
        const int s0 = wsum[0], s1 = wsum[1], s2 = wsum[2], s3 = wsum[3];
        const int b = atomicAdd(gcursor, s0 + s1 + s2 + s3);
        wsum[0] = b; wsum[1] = b + s0; wsum[2] = b + s0 + s1; wsum[3] = b + s0 + s1 + s2;
    }
    __syncthreads();
    if (i < n) offs[i] = wsum[wv] + excl;
}

// ---------------- single-pass non-atomic fill (classic path) ----------------
__global__ void fill_kernel(const int* __restrict__ dst, const int* __restrict__ src,
                            const float* __restrict__ e,
                            const int* __restrict__ offs, const int* __restrict__ rank,
                            int2* __restrict__ meta, int n_edges) {
    const int i = blockIdx.x * blockDim.x + threadIdx.x;
    if (i >= n_edges) return;
    const int d = dst[i];
    meta[offs[d] + rank[i]] = make_int2(src[i], __float_as_int(e[i]));
}

// ---------------- fused: precompute (blocks < pg) + count/scatter (blocks >= pg) ----------------
// precompute (R12 body, byte-for-byte). count role: atomic rank + scatter
// (padded) or rank store (classic). First count-role block (bid==pg) also packs
// W2 into w2p: w2p[q*256 + lane*4 + c] = W2[(4q+c)*64 + lane].
__global__ __launch_bounds__(256, 2) void pre_count_kernel(
    const float* __restrict__ h, const float* __restrict__ W1, const float* __restrict__ b1,
    unsigned short* __restrict__ abf, unsigned short* __restrict__ bsf, int n_nodes,
    const int* __restrict__ dst, const int* __restrict__ src, const float* __restrict__ e,
    int* __restrict__ counts, int2* __restrict__ meta2, int* __restrict__ rank,
    const float* __restrict__ W2, float* __restrict__ w2p,
    int n_edges, int pg, int padK)
{
    const int lane = threadIdx.x & 63;
    const int wv   = threadIdx.x >> 6;

    if ((int)blockIdx.x >= pg) {
        // ---- count (+scatter) role ----
        if ((int)blockIdx.x == pg) {
            // pack W2 -> w2p (4096 floats, 16 per thread), once per launch
            #pragma unroll
            for (int u = 0; u < 16; ++u) {
                const int idx = threadIdx.x * 16 + u;
                const int q = idx >> 8, l = (idx >> 2) & 63, c = idx & 3;
                w2p[idx] = W2[(size_t)(4 * q + c) * 64 + l];
            }
        }
        const int i = ((int)blockIdx.x - pg) * 256 + threadIdx.x;
        if (i < n_edges) {
            const int d = dst[i];
            const int r = atomicAdd(&counts[d], 1);
            if (padK > 0)
                meta2[(size_t)d * padK + r] = make_int2(src[i], __float_as_int(e[i]));
            else
                rank[i] = r;
        }
        return;
    }

    // ---- precompute role (R12 body) ----
    const int nbase = (blockIdx.x * 4 + wv) * 32;   // wave's 32 nodes
    if (nbase >= n_nodes) return;

    const float4* h4p = reinterpret_cast<const float4*>(h);

    auto ldgrp = [&](int g) -> float4 {
        float4 v = make_float4(0.f, 0.f, 0.f, 0.f);
        const int row = nbase + 4 * g + (lane >> 4);
        if (g < 8 && row < n_nodes)
            v = h4p[(size_t)(nbase + 4 * g) * 16 + lane];
        return v;
    };

    // ---- pass A: av over W1[0:64] -> abf ----
    {
        float wreg[64];
        #pragma unroll
        for (int k = 0; k < 64; ++k) wreg[k] = W1[(size_t)k * 64 + lane];
        #pragma unroll
        for (int k = 0; k < 64; ++k) asm volatile("" : "+v"(wreg[k]));

        float4 cur = ldgrp(0);
        for (int g = 0; g < 8; ++g) {
            const float4 nxt = ldgrp(g + 1);        // prefetch next group
            #pragma unroll
            for (int nn = 0; nn < 4; ++nn) {
                const int n = nbase + 4 * g + nn;
                if (n < n_nodes) {
                    float av = 0.f;
                    #pragma unroll
                    for (int k4 = 0; k4 < 16; ++k4) {
                        const int sl = nn * 16 + k4;   // imm lane after unroll
                        const float h0 = __uint_as_float(__builtin_amdgcn_readlane(__float_as_uint(cur.x), sl));
                        const float h1 = __uint_as_float(__builtin_amdgcn_readlane(__float_as_uint(cur.y), sl));
                        const float h2 = __uint_as_float(__builtin_amdgcn_readlane(__float_as_uint(cur.z), sl));
                        const float h3 = __uint_as_float(__builtin_amdgcn_readlane(__float_as_uint(cur.w), sl));
                        av = fmaf(h0, wreg[4 * k4 + 0], av);   // same chain order
                        av = fmaf(h1, wreg[4 * k4 + 1], av);
                        av = fmaf(h2, wreg[4 * k4 + 2], av);
                        av = fmaf(h3, wreg[4 * k4 + 3], av);
                    }
                    __hip_bfloat16 ab = __float2bfloat16(av);
                    abf[(size_t)n * 64 + lane] = *reinterpret_cast<unsigned short*>(&ab);
                }
            }
            cur = nxt;
        }
    }

    // ---- pass B: bv over W1[64:128] + b1 -> bsf ----
    {
        float wreg[64];
        #pragma unroll
        for (int k = 0; k < 64; ++k) wreg[k] = W1[(size_t)(64 + k) * 64 + lane];
        #pragma unroll
        for (int k = 0; k < 64; ++k) asm volatile("" : "+v"(wreg[k]));
        const float b1l = b1[lane];

        float4 cur = ldgrp(0);
        for (int g = 0; g < 8; ++g) {
            const float4 nxt = ldgrp(g + 1);
            #pragma unroll
            for (int nn = 0; nn < 4; ++nn) {
                const int n = nbase + 4 * g + nn;
                if (n < n_nodes) {
                    float bv = b1l;
                    #pragma unroll
                    for (int k4 = 0; k4 < 16; ++k4) {
                        const int sl = nn * 16 + k4;
                        const float h0 = __uint_as_float(__builtin_amdgcn_readlane(__float_as_uint(cur.x), sl));
                        const float h1 = __uint_as_float(__builtin_amdgcn_readlane(__float_as_uint(cur.y), sl));
                        const float h2 = __uint_as_float(__builtin_amdgcn_readlane(__float_as_uint(cur.z), sl));
                        const float h3 = __uint_as_float(__builtin_amdgcn_readlane(__float_as_uint(cur.w), sl));
                        bv = fmaf(h0, wreg[4 * k4 + 0], bv);   // same chain order
                        bv = fmaf(h1, wreg[4 * k4 + 1], bv);
                        bv = fmaf(h2, wreg[4 * k4 + 2], bv);
                        bv = fmaf(h3, wreg[4 * k4 + 3], bv);
                    }
                    __hip_bfloat16 bb = __float2bfloat16(bv);
                    bsf[(size_t)n * 64 + lane] = *reinterpret_cast<unsigned short*>(&bb);
                }
            }
            cur = nxt;
        }
    }
}

// ---------------- accum: wave/node, lane=feat, register-meta + depth-8 prefetch,
// ---------------- epilogue W2 via packed dwordx4 (16 loads/node, was 64) ----------------
__global__ __launch_bounds__(256) void node_accum_kernel(
    const unsigned short* __restrict__ abf, const unsigned short* __restrict__ bsf,
    const float* __restrict__ W1, const float* __restrict__ w2p, const float* __restrict__ b2,
    const int* __restrict__ offs, const int* __restrict__ counts,
    const int2* __restrict__ meta, float* __restrict__ out, int n_nodes, int padK)
{
    const int lane = threadIdx.x & 63;
    const int wv   = __builtin_amdgcn_readfirstlane(threadIdx.x >> 6);
    const int n    = blockIdx.x * 4 + wv;          // wave-uniform node id
    if (n >= n_nodes) return;

    const float basel = __uint_as_float((uint)bsf[(size_t)n * 64 + lane] << 16);
    const float w128l = W1[(size_t)128 * 64 + lane];
    float acc = 0.f;

    const int beg = (padK > 0) ? n * padK : offs[n];   // s_load / SALU (n uniform)
    const int np  = counts[n];                          // s_load

    // chunks of <=64 edges: meta staged into registers by ONE lane-parallel load,
    // per-edge src/e extracted with v_readlane (no memory on the gather-addr path)
    for (int c0 = 0; c0 < np; c0 += 64) {
        const int cn = min(np - c0, 64);

        int mx = 0, my = 0;
        if (lane < cn) {
            const int2 m = meta[beg + c0 + lane];   // 512B coalesced, once per chunk
            mx = m.x; my = m.y;
        }

        // pipeline slots hold the RAW zext ushort; <<16 happens at consume time
        uint x0=0,x1=0,x2=0,x3=0,x4=0,x5=0,x6=0,x7=0;

        auto ld = [&](int j, uint& x) {
            const int s = __builtin_amdgcn_readlane(mx, j);        // uniform src id
            x = (uint)abf[(size_t)s * 64 + lane];                  // saddr gather, 128B/wave
        };
        auto step = [&](int j, uint xr) {
            const float ev = __uint_as_float((uint)__builtin_amdgcn_readlane(my, j));
            const float xv = __uint_as_float(xr << 16);
            acc += fmaxf(fmaf(ev, w128l, basel) + xv, 0.f);
        };

        if (cn > 0) ld(0, x0);
        if (cn > 1) ld(1, x1);
        if (cn > 2) ld(2, x2);
        if (cn > 3) ld(3, x3);
        if (cn > 4) ld(4, x4);
        if (cn > 5) ld(5, x5);
        if (cn > 6) ld(6, x6);
        if (cn > 7) ld(7, x7);

        int i = 0;
        while (i + 16 <= cn) {
            step(i + 0, x0); ld(i + 8,  x0);
            step(i + 1, x1); ld(i + 9,  x1);
            step(i + 2, x2); ld(i + 10, x2);
            step(i + 3, x3); ld(i + 11, x3);
            step(i + 4, x4); ld(i + 12, x4);
            step(i + 5, x5); ld(i + 13, x5);
            step(i + 6, x6); ld(i + 14, x6);
            step(i + 7, x7); ld(i + 15, x7);
            i += 8;
        }
        const int r = cn - i;   // 0..15
        if (r > 0)  { step(i + 0, x0); }  if (r > 8)  { ld(i + 8,  x0); }
        if (r > 1)  { step(i + 1, x1); }  if (r > 9)  { ld(i + 9,  x1); }
        if (r > 2)  { step(i + 2, x2); }  if (r > 10) { ld(i + 10, x2); }
        if (r > 3)  { step(i + 3, x3); }  if (r > 11) { ld(i + 11, x3); }
        if (r > 4)  { step(i + 4, x4); }  if (r > 12) { ld(i + 12, x4); }
        if (r > 5)  { step(i + 5, x5); }  if (r > 13) { ld(i + 13, x5); }
        if (r > 6)  { step(i + 6, x6); }  if (r > 14) { ld(i + 14, x6); }
        if (r > 7)  { step(i + 7, x7); }
        if (r > 8)  { step(i + 8,  x0); }
        if (r > 9)  { step(i + 9,  x1); }
        if (r > 10) { step(i + 10, x2); }
        if (r > 11) { step(i + 11, x3); }
        if (r > 12) { step(i + 12, x4); }
        if (r > 13) { step(i + 13, x5); }
        if (r > 14) { step(i + 14, x6); }
    }

    // fused epilogue: out[n][lane] = sum_j acc_j * W2[j][lane] + np*b2[lane]
    // packed W2: 16x dwordx4 (lane stride 16B, coalesced, L1-hot); j = 4q+c
    // ascending -> identical fma order to the 64x dword version.
    float o = (float)np * b2[lane];
    const float4* w2p4 = reinterpret_cast<const float4*>(w2p);
    #pragma unroll
    for (int q = 0; q < 16; ++q) {
        const float4 w4 = w2p4[q * 64 + lane];
        o = fmaf(__shfl(acc, 4 * q + 0, 64), w4.x, o);     // v_readlane (imm)
        o = fmaf(__shfl(acc, 4 * q + 1, 64), w4.y, o);
        o = fmaf(__shfl(acc, 4 * q + 2, 64), w4.z, o);
        o = fmaf(__shfl(acc, 4 * q + 3, 64), w4.w, o);
    }
    out[(size_t)n * 64 + lane] = o;
}

extern "C" void kernel_launch(void* const* d_in, const int* in_sizes, int n_in,
                              void* d_out, int out_size, void* d_ws, size_t ws_size,
                              hipStream_t stream) {
    const float* h  = (const float*)d_in[0];
    const float* e  = (const float*)d_in[1];
    const int* src  = (const int*)d_in[2];
    const int* dst  = (const int*)d_in[3];
    const float* W1 = (const float*)d_in[4];
    const float* b1 = (const float*)d_in[5];
    const float* W2 = (const float*)d_in[6];
    const float* b2 = (const float*)d_in[7];
    float* out = (float*)d_out;

    const int n_edges = in_sizes[2];
    const int N = in_sizes[0] / 64;

    const int eb = (n_edges + 255) / 256;
    const int nb = (N + 255) / 256;
    const int pg = (N + PRE_NPB - 1) / PRE_NPB;

    // padded path: counts(N+8) + w2p(4096 f) + meta2(N*PADK int2) + abf/bsf(256N B)
    const size_t need_pad = ((size_t)N + 8) * sizeof(int) + 4096 * sizeof(float)
                          + (size_t)N * PADK * sizeof(int2)
                          + (size_t)N * 256;

    int* counts = (int*)d_ws;

    if (ws_size >= need_pad) {
        // ---- padded path: memset -> pre_count(+scatter+pack) -> node_accum ----
        float* w2p  = (float*)(counts + N + 8);
        int2* meta2 = (int2*)(w2p + 4096);
        unsigned short* abf = (unsigned short*)(meta2 + (size_t)N * PADK);
        unsigned short* bsf = abf + (size_t)64 * N;

        hipMemsetAsync(counts, 0, ((size_t)N + 8) * sizeof(int), stream);
        pre_count_kernel<<<pg + eb, 256, 0, stream>>>(h, W1, b1, abf, bsf, N,
                                                      dst, src, e, counts, meta2,
                                                      nullptr, W2, w2p,
                                                      n_edges, pg, PADK);
        node_accum_kernel<<<(N + 3) / 4, 256, 0, stream>>>(abf, bsf, W1, w2p, b2,
                                                           nullptr, counts, meta2,
                                                           out, N, PADK);
    } else {
        // ---- classic path (R12 pipeline + packed-W2 epilogue) ----
        float* w2p   = (float*)(counts + N + 8);
        int* gcursor = (int*)(w2p + 4096);
        int* offs    = gcursor + 8;
        int* rank    = offs + N;
        int2* meta   = (int2*)(rank + n_edges);
        unsigned short* abf = (unsigned short*)(meta + n_edges);
        unsigned short* bsf = abf + (size_t)64 * N;

        hipMemsetAsync(counts, 0, ((size_t)N + 8) * sizeof(int), stream);
        hipMemsetAsync(gcursor, 0, 8 * sizeof(int), stream);
        pre_count_kernel<<<pg + eb, 256, 0, stream>>>(h, W1, b1, abf, bsf, N,
                                                      dst, src, e, counts, nullptr,
                                                      rank, W2, w2p,
                                                      n_edges, pg, 0);
        alloc_offs_kernel<<<nb, 256, 0, stream>>>(counts, gcursor, offs, N);
        fill_kernel<<<eb, 256, 0, stream>>>(dst, src, e, offs, rank, meta, n_edges);
        node_accum_kernel<<<(N + 3) / 4, 256, 0, stream>>>(abf, bsf, W1, w2p, b2,
                                                           offs, counts, meta,
                                                           out, N, 0);
    }
}